// Round 9
// baseline (5176.792 us; speedup 1.0000x reference)
//
#include <hip/hip_runtime.h>
#include <hip/hip_bf16.h>

// 2-layer GRU decoder, persistent MFMA kernel. B=128, T=1024, H=200.
// 8 batch-groups (16 batch each) x 16 hidden-slice blocks = 128 blocks.
// Weights live in REGISTERS as bf16 hi/lo MFMA A-fragments; per-step GEMM via
// mfma_f32_16x16x32_bf16 x3 (hi*hi + hi*lo + lo*hi) for fp32-grade precision.
// R12 = R8 (2998us, proven) with three latency trims; exchange LAYOUT and
// staging loads are byte-identical to R8 (R11 proved touching the load side
// regresses: FETCH 2x, LDS conflicts +68%, dur +250us despite WRITE 3x down):
//  1) gate-thread remap cb=tid/hs, cj=tid%hs -> 13 consecutive lanes store
//     52 contiguous bytes (32 segments vs 416 scattered dwords -> short drain).
//     Wi0 stored transposed (Wi0t[8][39]) so its gate reads stay stride-1.
//  2) per-wave flags: each wave drains its OWN stores (vmcnt0) and flags;
//     removes one __syncthreads. Poll stays ONE wave/block (R7/R10 lesson:
//     poll concurrency kills the LLC), 64 words = 2 lines per iteration.
//  3) no s_sleep in poll (load RT self-throttles, ~600cy/iter).
// Lessons held: scope is no lever (R9); RMW chain is cheap (R8); store BW is
// not the path (R11); all-thread polling catastrophic (R7/R10).

#define TT 1024
#define HH 200
#define NB 16
#define HS 13
#define KP 232   // hB row stride in ushorts; 464 B = 29*16 -> b128-aligned

typedef __attribute__((ext_vector_type(8))) short short8;
typedef __attribute__((ext_vector_type(4))) float f32x4;

__device__ __forceinline__ float sigm(float v) { return 1.0f / (1.0f + __expf(-v)); }
__device__ __forceinline__ float tanh_fast(float v) {
  float e = __expf(-2.0f * v);
  return (1.0f - e) / (1.0f + e);
}
__device__ __forceinline__ uint llc_load_u32(const uint* p) {
  return __hip_atomic_load(p, __ATOMIC_RELAXED, __HIP_MEMORY_SCOPE_SYSTEM);
}
__device__ __forceinline__ void llc_store_u32(uint* p, uint v) {
  __hip_atomic_store(p, v, __ATOMIC_RELAXED, __HIP_MEMORY_SCOPE_SYSTEM);
}
__device__ __forceinline__ float bfu2f(ushort u) {
  return __uint_as_float(((uint)u) << 16);
}
__device__ __forceinline__ ushort f2bfu(float f) {
  __hip_bfloat16 b = __float2bfloat16(f);
  return *(ushort*)&b;
}
__device__ __forceinline__ uint packf(float h) {
  ushort hi = f2bfu(h);
  float  fh = bfu2f(hi);
  ushort lo = f2bfu(h - fh);
  return (uint)hi | ((uint)lo << 16);
}

__global__ __launch_bounds__(256, 1) void gru2_mfma(
    const float* __restrict__ x,
    const float* __restrict__ Wih0, const float* __restrict__ Whh0,
    const float* __restrict__ bih0, const float* __restrict__ bhh0,
    const float* __restrict__ Wih1, const float* __restrict__ Whh1,
    const float* __restrict__ bih1, const float* __restrict__ bhh1,
    const float* __restrict__ Wfc,  const float* __restrict__ bfc,
    float* __restrict__ out,
    uint* __restrict__ h0g, uint* __restrict__ h1g, uint* __restrict__ syncp)
{
  // LDS: bf16 hi/lo planes of h0,h1 (B-operand layout), D results, misc.
  __shared__ __align__(16) ushort hBh[2][NB][KP];
  __shared__ __align__(16) ushort hBl[2][NB][KP];
  __shared__ float D[117][17];
  __shared__ float Wi0t[8][39];     // transposed: stride-1 reads under new map
  __shared__ float bi0[39], bh0[39], bi1[39], bh1[39], bfs[4];
  __shared__ float xc[NB][8];

  const int tid  = threadIdx.x;
  const int wave = tid >> 6;
  const int lane = tid & 63;
  const int m15  = lane & 15;   // MFMA row (A) / col (B,C)
  const int q    = lane >> 4;   // MFMA quad

  const int g  = blockIdx.x & 7;    // batch-group
  const int s  = blockIdx.x >> 3;   // hidden-slice
  const int b0 = g * NB;
  const int j0 = s * HS;
  const int hs = (HH - j0 < HS) ? (HH - j0) : HS;   // 13 (s<15) or 5 (s==15)
  const int th   = 3 * hs;
  const int h0r  = 6 * hs;                          // rows dotted with h0
  const int T0   = (h0r + 15) >> 4;                 // 5 or 2  (h0 tiles)
  const int NT   = T0 + ((th + 15) >> 4);           // 8 or 3  (total tiles)
  const bool isOut = (s == 15);

  // sync region (512 u32, footprint identical to proven R3/R8):
  // per-wave flag(g,s,w) at syncp[g*64 + s*4 + w]; max 7*64+63 = 511 < 512.
  uint* flags = syncp;

  // ---- one-time: weight A-fragments into registers (hi/lo bf16) ----
  short8 Ah[2][7], Al[2][7];
  #pragma unroll
  for (int mt = 0; mt < 2; ++mt) {
    const int T = wave * 2 + mt;
    const bool fc  = isOut && (wave == 2) && (mt == 0);
    const bool val = fc || (T < NT);
    #pragma unroll
    for (int kt = 0; kt < 7; ++kt) {
      short8 vh = {0,0,0,0,0,0,0,0}, vl = {0,0,0,0,0,0,0,0};
      #pragma unroll
      for (int j = 0; j < 8; ++j) {
        const int k = kt * 32 + q * 8 + j;
        float w = 0.0f;
        if (val && k < HH) {
          if (fc) {
            if (m15 < 4) w = Wfc[m15 * HH + k];
          } else {
            const int p = T * 16 + m15;
            int r = -1;
            if (p < h0r) r = p;
            else if (p >= T0 * 16 && (p - T0 * 16) < th) r = h0r + (p - T0 * 16);
            if (r >= 0) {
              const int m  = r / th, rr = r - m * th;
              const int qq = rr / hs, jj = rr - qq * hs;
              const float* src = (m == 0) ? Whh0 : ((m == 1) ? Wih1 : Whh1);
              w = src[(qq * HH + j0 + jj) * HH + k];
            }
          }
        }
        const ushort uh = f2bfu(w);
        const ushort ul = f2bfu(w - bfu2f(uh));
        vh[j] = (short)uh; vl[j] = (short)ul;
      }
      Ah[mt][kt] = vh; Al[mt][kt] = vl;
    }
  }

  // ---- one-time: small LDS tables ----
  for (int u = tid; u < th * 8; u += 256) {
    int rr = u >> 3, c = u & 7;
    int qq = rr / hs, jj = rr - qq * hs;
    Wi0t[c][rr] = Wih0[(qq * HH + j0 + jj) * 8 + c];
  }
  for (int u = tid; u < th; u += 256) {
    int qq = u / hs, jj = u - qq * hs;
    int grow = qq * HH + j0 + jj;
    bi0[u] = bih0[grow]; bh0[u] = bhh0[grow];
    bi1[u] = bih1[grow]; bh1[u] = bhh1[grow];
  }
  if (tid < 4) bfs[tid] = bfc[tid];
  for (int u = tid; u < 2 * NB * KP / 2; u += 256) ((uint*)hBh)[u] = 0;  // zero pads
  for (int u = tid; u < 2 * NB * KP / 2; u += 256) ((uint*)hBl)[u] = 0;
  // Emotion columns of xc are t-invariant: write once.
  if (tid < 128 && (tid & 7) >= 4)
    xc[tid >> 3][tid & 7] = x[(b0 + (tid >> 3)) * TT * 8 + (tid & 7)];
  __syncthreads();

  // Gate-combine remap: cb = tid/hs (batch), cj = tid%hs (k in slice).
  // 13 consecutive lanes -> 52 contiguous bytes per h store segment.
  const int gt = 16 * hs;
  const int cb = tid / hs;
  const int cj = tid - cb * hs;
  const int xb = tid >> 3, xcc7 = tid & 7;  // xc staging indices

  for (int t = 0; t <= TT + 1; ++t) {
    // ---- hoist teacher-forcing x load (overlaps staging round trip) ----
    float xtf = 1.0f;
    if (tid < 128 && xcc7 < 4 && t > 0 && t < TT)
      xtf = x[((b0 + xb) * TT + (t - 1)) * 8 + xcc7];

    // ---- stage h0(t-1), h1(t-2): byte-identical to R8 (proven) ----
    const uint* h0src = h0g + ((t + 1) & 1) * (128 * HH);
    const uint* h1src = h1g + (t & 1) * (128 * HH);
    uint tmp[25];                          // 2 states x 16 b x 200 k = 6400
    #pragma unroll
    for (int i = 0; i < 25; ++i) {
      const int u  = tid + i * 256;
      const int st = u / 3200, rem = u - st * 3200;
      const int b  = rem / 200, k = rem - b * 200;
      tmp[i] = llc_load_u32(&(st ? h1src : h0src)[(b0 + b) * HH + k]);
    }
    #pragma unroll
    for (int i = 0; i < 25; ++i) {
      const int u  = tid + i * 256;
      const int st = u / 3200, rem = u - st * 3200;
      const int b  = rem / 200, k = rem - b * 200;
      hBh[st][b][k] = (ushort)(tmp[i] & 0xffff);
      hBl[st][b][k] = (ushort)(tmp[i] >> 16);
    }
    if (tid < 128 && xcc7 < 4 && t < TT)   // tf columns (t==0 -> 1.0f)
      xc[xb][xcc7] = xtf;
    __syncthreads();

    // ---- MFMA: D[rows x 16 batch] = W * h  (bf16x3) ----
    #pragma unroll
    for (int mt = 0; mt < 2; ++mt) {
      const int T = wave * 2 + mt;
      const bool fc  = isOut && (wave == 2) && (mt == 0);
      const bool val = fc || (T < NT);
      if (!val) continue;
      const int st = fc ? 1 : ((T < T0) ? 0 : 1);
      const ushort* Bh = &hBh[st][m15][0];
      const ushort* Bl = &hBl[st][m15][0];
      f32x4 acc = {0.f, 0.f, 0.f, 0.f};
      #pragma unroll
      for (int kt = 0; kt < 7; ++kt) {
        const short8 bh = *(const short8*)&Bh[kt * 32 + q * 8];
        const short8 bl = *(const short8*)&Bl[kt * 32 + q * 8];
        acc = __builtin_amdgcn_mfma_f32_16x16x32_bf16(Ah[mt][kt], bh, acc, 0, 0, 0);
        acc = __builtin_amdgcn_mfma_f32_16x16x32_bf16(Ah[mt][kt], bl, acc, 0, 0, 0);
        acc = __builtin_amdgcn_mfma_f32_16x16x32_bf16(Al[mt][kt], bh, acc, 0, 0, 0);
      }
      if (fc) {                              // FC head: out(t-2)
        if (t >= 2) {
          #pragma unroll
          for (int i = 0; i < 4; ++i) {
            const int p = q * 4 + i;
            if (p < 4)
              out[((b0 + m15) * TT + (t - 2)) * 4 + p] = tanh_fast(acc[i] + bfs[p]);
          }
        }
      } else {
        #pragma unroll
        for (int i = 0; i < 4; ++i) {
          const int p = T * 16 + q * 4 + i;
          int r = -1;
          if (p < h0r) r = p;
          else if (p >= T0 * 16 && (p - T0 * 16) < th) r = h0r + (p - T0 * 16);
          if (r >= 0) D[r][m15] = acc[i];
        }
      }
    }
    __syncthreads();

    // ---- gate combine + semi-coalesced stores (R8 layout, remapped lanes) --
    if (tid < gt) {
      const float hv0 = bfu2f(hBh[0][cb][j0 + cj]) + bfu2f(hBl[0][cb][j0 + cj]);
      const float hv1 = bfu2f(hBh[1][cb][j0 + cj]) + bfu2f(hBl[1][cb][j0 + cj]);
      if (t < TT) {                       // h0(t)
        float ir = bi0[cj], iz = bi0[hs + cj], in_ = bi0[2 * hs + cj];
        #pragma unroll
        for (int c = 0; c < 8; ++c) {
          const float xv = xc[cb][c];
          ir  += Wi0t[c][cj] * xv;
          iz  += Wi0t[c][hs + cj] * xv;
          in_ += Wi0t[c][2 * hs + cj] * xv;
        }
        const float hr = D[cj][cb] + bh0[cj];
        const float hz = D[hs + cj][cb] + bh0[hs + cj];
        const float hn = D[2 * hs + cj][cb] + bh0[2 * hs + cj];
        const float r = sigm(ir + hr), z = sigm(iz + hz);
        const float n = tanh_fast(in_ + r * hn);
        llc_store_u32(&h0g[(t & 1) * (128 * HH) + (b0 + cb) * HH + j0 + cj],
                      packf((1.0f - z) * n + z * hv0));
      }
      if (t >= 1 && t <= TT) {            // h1(t-1)
        const float ir  = D[3 * hs + cj][cb] + bi1[cj];
        const float iz  = D[4 * hs + cj][cb] + bi1[hs + cj];
        const float in_ = D[5 * hs + cj][cb] + bi1[2 * hs + cj];
        const float hr  = D[6 * hs + cj][cb] + bh1[cj];
        const float hz  = D[7 * hs + cj][cb] + bh1[hs + cj];
        const float hn  = D[8 * hs + cj][cb] + bh1[2 * hs + cj];
        const float r = sigm(ir + hr), z = sigm(iz + hz);
        const float n = tanh_fast(in_ + r * hn);
        llc_store_u32(&h1g[((t + 1) & 1) * (128 * HH) + (b0 + cb) * HH + j0 + cj],
                      packf((1.0f - z) * n + z * hv1));
      }
    }

    // ---- per-wave flags + ONE poll wave per block ----
    // Each wave drains ITS OWN h stores (vmcnt 0) then flags -> no block sync
    // needed before flagging. Poll passing proves every wave of every block
    // finished gates (stores data-depend on the LDS reads of hB/xc/D), so
    // staging for t+1 cannot race gate reads of t.
    asm volatile("s_waitcnt vmcnt(0)" ::: "memory");
    if (lane == 0)
      llc_store_u32(&flags[g * 64 + s * 4 + wave], (uint)(t + 1));
    if (wave == 0) {
      const uint tgt = (uint)(t + 1);
      const uint* fp = &flags[g * 64 + lane];   // 64 words = 2 lines
      // Bounded poll (fail-visible instead of harness-killing hang).
      for (int it = 0; it < 200000; ++it) {
        const uint v = llc_load_u32(fp);
        if (__all((int)(v >= tgt))) break;
      }
    }
    __syncthreads();
  }
}

extern "C" void kernel_launch(void* const* d_in, const int* in_sizes, int n_in,
                              void* d_out, int out_size, void* d_ws, size_t ws_size,
                              hipStream_t stream) {
  uint* ws = (uint*)d_ws;
  // ws layout (u32): h0g[2][128][200] @0, h1g[2][128][200] @51200,
  // per-wave flags (512 u32) @102400. Footprint identical to proven R3/R8.
  hipMemsetAsync(d_ws, 0, (size_t)(102400 + 512) * sizeof(uint), stream);
  gru2_mfma<<<128, 256, 0, stream>>>(
      (const float*)d_in[0],
      (const float*)d_in[1], (const float*)d_in[2],
      (const float*)d_in[3], (const float*)d_in[4],
      (const float*)d_in[5], (const float*)d_in[6],
      (const float*)d_in[7], (const float*)d_in[8],
      (const float*)d_in[9], (const float*)d_in[10],
      (float*)d_out, ws, ws + 51200, ws + 102400);
}

// Round 10
// 2926.149 us; speedup vs baseline: 1.7691x; 1.7691x over previous
//
#include <hip/hip_runtime.h>
#include <hip/hip_bf16.h>

// 2-layer GRU decoder, persistent MFMA kernel. B=128, T=1024, H=200.
// 8 batch-groups (16 batch each) x 16 hidden-slice blocks = 128 blocks.
// Weights live in REGISTERS as bf16 hi/lo MFMA A-fragments; per-step GEMM via
// mfma_f32_16x16x32_bf16 x3 (hi*hi + hi*lo + lo*hi) for fp32-grade precision.
// R13 = R8 (2998us, proven) + EXACTLY ONE change: gate-thread remap
// cb=tid/hs, cj=tid%hs so 13 consecutive lanes store 52 contiguous bytes of
// h (32 segments/block-step vs 416 scattered dwords) -> shorter vmcnt(0)
// drain at the pre-flag __syncthreads. Wi0 stored transposed (Wi0t[8][39])
// so its gate reads stay stride-1/broadcast. Barrier structure, staging,
// flag placement, poll (16-lane, s_sleep, one wave per block) are R8-verbatim.
// Evidence: R12 bundled this remap with barrier changes and regressed 73% --
// counters showed the remap itself healthy (WRITE 653->358MB, conflicts
// 7.75e7->7.12e7); the regression was per-wave flag stores thrashing the
// polled lines (R7's mechanism). This round isolates the remap.
// Lessons held: scope no lever (R9); RMWs pipeline (R8); load-side layout
// untouchable (R11); poll stays one sleepy wave per block (R7/R10/R12).

#define TT 1024
#define HH 200
#define NB 16
#define HS 13
#define KP 232   // hB row stride in ushorts; 464 B = 29*16 -> b128-aligned

typedef __attribute__((ext_vector_type(8))) short short8;
typedef __attribute__((ext_vector_type(4))) float f32x4;

__device__ __forceinline__ float sigm(float v) { return 1.0f / (1.0f + __expf(-v)); }
__device__ __forceinline__ float tanh_fast(float v) {
  float e = __expf(-2.0f * v);
  return (1.0f - e) / (1.0f + e);
}
__device__ __forceinline__ uint llc_load_u32(const uint* p) {
  return __hip_atomic_load(p, __ATOMIC_RELAXED, __HIP_MEMORY_SCOPE_SYSTEM);
}
__device__ __forceinline__ void llc_store_u32(uint* p, uint v) {
  __hip_atomic_store(p, v, __ATOMIC_RELAXED, __HIP_MEMORY_SCOPE_SYSTEM);
}
__device__ __forceinline__ float bfu2f(ushort u) {
  return __uint_as_float(((uint)u) << 16);
}
__device__ __forceinline__ ushort f2bfu(float f) {
  __hip_bfloat16 b = __float2bfloat16(f);
  return *(ushort*)&b;
}
__device__ __forceinline__ uint packf(float h) {
  ushort hi = f2bfu(h);
  float  fh = bfu2f(hi);
  ushort lo = f2bfu(h - fh);
  return (uint)hi | ((uint)lo << 16);
}

__global__ __launch_bounds__(256, 1) void gru2_mfma(
    const float* __restrict__ x,
    const float* __restrict__ Wih0, const float* __restrict__ Whh0,
    const float* __restrict__ bih0, const float* __restrict__ bhh0,
    const float* __restrict__ Wih1, const float* __restrict__ Whh1,
    const float* __restrict__ bih1, const float* __restrict__ bhh1,
    const float* __restrict__ Wfc,  const float* __restrict__ bfc,
    float* __restrict__ out,
    uint* __restrict__ h0g, uint* __restrict__ h1g, uint* __restrict__ syncp)
{
  // LDS: bf16 hi/lo planes of h0,h1 (B-operand layout), D results, misc.
  __shared__ __align__(16) ushort hBh[2][NB][KP];
  __shared__ __align__(16) ushort hBl[2][NB][KP];
  __shared__ float D[117][17];
  __shared__ float Wi0t[8][39];     // transposed: clean reads under remap
  __shared__ float bi0[39], bh0[39], bi1[39], bh1[39], bfs[4];
  __shared__ float xc[NB][8];

  const int tid  = threadIdx.x;
  const int wave = tid >> 6;
  const int lane = tid & 63;
  const int m15  = lane & 15;   // MFMA row (A) / col (B,C)
  const int q    = lane >> 4;   // MFMA quad

  const int g  = blockIdx.x & 7;    // batch-group
  const int s  = blockIdx.x >> 3;   // hidden-slice
  const int b0 = g * NB;
  const int j0 = s * HS;
  const int hs = (HH - j0 < HS) ? (HH - j0) : HS;   // 13 (s<15) or 5 (s==15)
  const int th   = 3 * hs;
  const int h0r  = 6 * hs;                          // rows dotted with h0
  const int T0   = (h0r + 15) >> 4;                 // 5 or 2  (h0 tiles)
  const int NT   = T0 + ((th + 15) >> 4);           // 8 or 3  (total tiles)
  const bool isOut = (s == 15);

  // sync region (512 u32, footprint identical to proven R3/R8):
  // flag(g,s) at syncp[g*64 + s*4] -- 16B spacing, R8-verbatim.
  uint* flags = syncp;

  // ---- one-time: weight A-fragments into registers (hi/lo bf16) ----
  short8 Ah[2][7], Al[2][7];
  #pragma unroll
  for (int mt = 0; mt < 2; ++mt) {
    const int T = wave * 2 + mt;
    const bool fc  = isOut && (wave == 2) && (mt == 0);
    const bool val = fc || (T < NT);
    #pragma unroll
    for (int kt = 0; kt < 7; ++kt) {
      short8 vh = {0,0,0,0,0,0,0,0}, vl = {0,0,0,0,0,0,0,0};
      #pragma unroll
      for (int j = 0; j < 8; ++j) {
        const int k = kt * 32 + q * 8 + j;
        float w = 0.0f;
        if (val && k < HH) {
          if (fc) {
            if (m15 < 4) w = Wfc[m15 * HH + k];
          } else {
            const int p = T * 16 + m15;
            int r = -1;
            if (p < h0r) r = p;
            else if (p >= T0 * 16 && (p - T0 * 16) < th) r = h0r + (p - T0 * 16);
            if (r >= 0) {
              const int m  = r / th, rr = r - m * th;
              const int qq = rr / hs, jj = rr - qq * hs;
              const float* src = (m == 0) ? Whh0 : ((m == 1) ? Wih1 : Whh1);
              w = src[(qq * HH + j0 + jj) * HH + k];
            }
          }
        }
        const ushort uh = f2bfu(w);
        const ushort ul = f2bfu(w - bfu2f(uh));
        vh[j] = (short)uh; vl[j] = (short)ul;
      }
      Ah[mt][kt] = vh; Al[mt][kt] = vl;
    }
  }

  // ---- one-time: small LDS tables ----
  for (int u = tid; u < th * 8; u += 256) {
    int rr = u >> 3, c = u & 7;
    int qq = rr / hs, jj = rr - qq * hs;
    Wi0t[c][rr] = Wih0[(qq * HH + j0 + jj) * 8 + c];
  }
  for (int u = tid; u < th; u += 256) {
    int qq = u / hs, jj = u - qq * hs;
    int grow = qq * HH + j0 + jj;
    bi0[u] = bih0[grow]; bh0[u] = bhh0[grow];
    bi1[u] = bih1[grow]; bh1[u] = bhh1[grow];
  }
  if (tid < 4) bfs[tid] = bfc[tid];
  for (int u = tid; u < 2 * NB * KP / 2; u += 256) ((uint*)hBh)[u] = 0;  // zero pads
  for (int u = tid; u < 2 * NB * KP / 2; u += 256) ((uint*)hBl)[u] = 0;
  // Emotion columns of xc are t-invariant: write once.
  if (tid < 128 && (tid & 7) >= 4)
    xc[tid >> 3][tid & 7] = x[(b0 + (tid >> 3)) * TT * 8 + (tid & 7)];
  __syncthreads();

  // Gate-combine remap (THE one change vs R8): cb = tid/hs, cj = tid%hs.
  // 13 consecutive lanes -> 52 contiguous bytes per h store segment.
  const int gt = 16 * hs;
  const int cb = tid / hs;
  const int cj = tid - cb * hs;
  const int xb = tid >> 3, xcc7 = tid & 7;  // xc staging indices

  for (int t = 0; t <= TT + 1; ++t) {
    // ---- hoist teacher-forcing x load (overlaps staging round trip) ----
    float xtf = 1.0f;
    if (tid < 128 && xcc7 < 4 && t > 0 && t < TT)
      xtf = x[((b0 + xb) * TT + (t - 1)) * 8 + xcc7];

    // ---- stage h0(t-1), h1(t-2): byte-identical to R8 (proven) ----
    const uint* h0src = h0g + ((t + 1) & 1) * (128 * HH);
    const uint* h1src = h1g + (t & 1) * (128 * HH);
    uint tmp[25];                          // 2 states x 16 b x 200 k = 6400
    #pragma unroll
    for (int i = 0; i < 25; ++i) {
      const int u  = tid + i * 256;
      const int st = u / 3200, rem = u - st * 3200;
      const int b  = rem / 200, k = rem - b * 200;
      tmp[i] = llc_load_u32(&(st ? h1src : h0src)[(b0 + b) * HH + k]);
    }
    #pragma unroll
    for (int i = 0; i < 25; ++i) {
      const int u  = tid + i * 256;
      const int st = u / 3200, rem = u - st * 3200;
      const int b  = rem / 200, k = rem - b * 200;
      hBh[st][b][k] = (ushort)(tmp[i] & 0xffff);
      hBl[st][b][k] = (ushort)(tmp[i] >> 16);
    }
    if (tid < 128 && xcc7 < 4 && t < TT)   // tf columns (t==0 -> 1.0f)
      xc[xb][xcc7] = xtf;
    __syncthreads();

    // ---- MFMA: D[rows x 16 batch] = W * h  (bf16x3) ----
    #pragma unroll
    for (int mt = 0; mt < 2; ++mt) {
      const int T = wave * 2 + mt;
      const bool fc  = isOut && (wave == 2) && (mt == 0);
      const bool val = fc || (T < NT);
      if (!val) continue;
      const int st = fc ? 1 : ((T < T0) ? 0 : 1);
      const ushort* Bh = &hBh[st][m15][0];
      const ushort* Bl = &hBl[st][m15][0];
      f32x4 acc = {0.f, 0.f, 0.f, 0.f};
      #pragma unroll
      for (int kt = 0; kt < 7; ++kt) {
        const short8 bh = *(const short8*)&Bh[kt * 32 + q * 8];
        const short8 bl = *(const short8*)&Bl[kt * 32 + q * 8];
        acc = __builtin_amdgcn_mfma_f32_16x16x32_bf16(Ah[mt][kt], bh, acc, 0, 0, 0);
        acc = __builtin_amdgcn_mfma_f32_16x16x32_bf16(Ah[mt][kt], bl, acc, 0, 0, 0);
        acc = __builtin_amdgcn_mfma_f32_16x16x32_bf16(Al[mt][kt], bh, acc, 0, 0, 0);
      }
      if (fc) {                              // FC head: out(t-2)
        if (t >= 2) {
          #pragma unroll
          for (int i = 0; i < 4; ++i) {
            const int p = q * 4 + i;
            if (p < 4)
              out[((b0 + m15) * TT + (t - 2)) * 4 + p] = tanh_fast(acc[i] + bfs[p]);
          }
        }
      } else {
        #pragma unroll
        for (int i = 0; i < 4; ++i) {
          const int p = T * 16 + q * 4 + i;
          int r = -1;
          if (p < h0r) r = p;
          else if (p >= T0 * 16 && (p - T0 * 16) < th) r = h0r + (p - T0 * 16);
          if (r >= 0) D[r][m15] = acc[i];
        }
      }
    }
    __syncthreads();

    // ---- gate combine + coalesced stores (remapped lanes, R8 layout) ----
    if (tid < gt) {
      const float hv0 = bfu2f(hBh[0][cb][j0 + cj]) + bfu2f(hBl[0][cb][j0 + cj]);
      const float hv1 = bfu2f(hBh[1][cb][j0 + cj]) + bfu2f(hBl[1][cb][j0 + cj]);
      if (t < TT) {                       // h0(t)
        float ir = bi0[cj], iz = bi0[hs + cj], in_ = bi0[2 * hs + cj];
        #pragma unroll
        for (int c = 0; c < 8; ++c) {
          const float xv = xc[cb][c];
          ir  += Wi0t[c][cj] * xv;
          iz  += Wi0t[c][hs + cj] * xv;
          in_ += Wi0t[c][2 * hs + cj] * xv;
        }
        const float hr = D[cj][cb] + bh0[cj];
        const float hz = D[hs + cj][cb] + bh0[hs + cj];
        const float hn = D[2 * hs + cj][cb] + bh0[2 * hs + cj];
        const float r = sigm(ir + hr), z = sigm(iz + hz);
        const float n = tanh_fast(in_ + r * hn);
        llc_store_u32(&h0g[(t & 1) * (128 * HH) + (b0 + cb) * HH + j0 + cj],
                      packf((1.0f - z) * n + z * hv0));
      }
      if (t >= 1 && t <= TT) {            // h1(t-1)
        const float ir  = D[3 * hs + cj][cb] + bi1[cj];
        const float iz  = D[4 * hs + cj][cb] + bi1[hs + cj];
        const float in_ = D[5 * hs + cj][cb] + bi1[2 * hs + cj];
        const float hr  = D[6 * hs + cj][cb] + bh1[cj];
        const float hz  = D[7 * hs + cj][cb] + bh1[hs + cj];
        const float hn  = D[8 * hs + cj][cb] + bh1[2 * hs + cj];
        const float r = sigm(ir + hr), z = sigm(iz + hz);
        const float n = tanh_fast(in_ + r * hn);
        llc_store_u32(&h1g[((t + 1) & 1) * (128 * HH) + (b0 + cb) * HH + j0 + cj],
                      packf((1.0f - z) * n + z * hv1));
      }
    }

    // ---- per-group barrier: R8-verbatim ----
    // __syncthreads drains every wave's h stores (s_waitcnt vmcnt(0) before
    // s_barrier), so the flag store is release-ordered after all h stores.
    __syncthreads();
    if (tid == 0)
      llc_store_u32(&flags[g * 64 + s * 4], (uint)(t + 1));
    if (wave == 0) {
      const uint tgt = (uint)(t + 1);
      const uint* fp = &flags[g * 64 + (lane & 15) * 4];
      // Bounded poll (fail-visible instead of harness-killing hang).
      for (int it = 0; it < 200000; ++it) {
        uint v = tgt;
        if (lane < 16) v = llc_load_u32(fp);
        if (__all((int)(v >= tgt))) break;
        __builtin_amdgcn_s_sleep(1);
      }
    }
    __syncthreads();
  }
}

extern "C" void kernel_launch(void* const* d_in, const int* in_sizes, int n_in,
                              void* d_out, int out_size, void* d_ws, size_t ws_size,
                              hipStream_t stream) {
  uint* ws = (uint*)d_ws;
  // ws layout (u32): h0g[2][128][200] @0, h1g[2][128][200] @51200,
  // flags (512 u32) @102400. Footprint identical to proven R3/R8.
  hipMemsetAsync(d_ws, 0, (size_t)(102400 + 512) * sizeof(uint), stream);
  gru2_mfma<<<128, 256, 0, stream>>>(
      (const float*)d_in[0],
      (const float*)d_in[1], (const float*)d_in[2],
      (const float*)d_in[3], (const float*)d_in[4],
      (const float*)d_in[5], (const float*)d_in[6],
      (const float*)d_in[7], (const float*)d_in[8],
      (const float*)d_in[9], (const float*)d_in[10],
      (float*)d_out, ws, ws + 51200, ws + 102400);
}